// Round 6
// baseline (3272.296 us; speedup 1.0000x reference)
//
#include <hip/hip_runtime.h>
#include <stdint.h>
#include <stddef.h>

// ---------------------------------------------------------------------------
// LSTM (B=64, T=1024, I=256, H=512) + attention pooling on MI355X (gfx950).
//   k_lstm v5: 64 blocks x 512 thr; block (bg,ug) = 16 batches x 32 units.
//   vs R5: consumer side is PER-PRODUCER parallel. Wave w owns producers
//   {2w, 2w+1}: it polls only their 2 flags (coalesced dwordx2, no sleep)
//   and coop-loads their 2 KB of h(t-1) into LDS as soon as they flag.
//   Early producers' detect+load overlap the straggler's; the 16 KB
//   lockstep burst (R5: ~4K simultaneous MALL requests/chain) is spread
//   in time. Quad MFMA accumulators (dep chain 8 -> 4).
//   Producer side unchanged: LDS-gather -> 16 x 64B line stores (sc0 sc1),
//   vmcnt drain, per-producer flag word. 4 independent batch-group chains.
// ---------------------------------------------------------------------------

typedef _Float16 f16_t;
typedef _Float16 half8 __attribute__((ext_vector_type(8)));
typedef float f32x4 __attribute__((ext_vector_type(4)));
typedef unsigned int uint2v __attribute__((ext_vector_type(2)));

#define MFMA16(a, b, c) __builtin_amdgcn_mfma_f32_16x16x32_f16((a), (b), (c), 0, 0, 0)

static constexpr int BATCH = 64;
static constexpr int TLEN = 1024;
static constexpr int IDIM = 256;
static constexpr int HDIM = 512;

__device__ __forceinline__ float sigf(float x) { return 1.f / (1.f + __expf(-x)); }
__device__ __forceinline__ float tanh_fast(float x) {
  float e = __expf(2.f * fabsf(x));
  float t = 1.f - 2.f / (e + 1.f);
  return copysignf(t, x);
}
__device__ __forceinline__ half8 load_cvt8(const float* p) {
  f32x4 a = *(const f32x4*)p;
  f32x4 b = *(const f32x4*)(p + 4);
  half8 r;
#pragma unroll
  for (int j = 0; j < 4; ++j) { r[j] = (f16_t)a[j]; r[4 + j] = (f16_t)b[j]; }
  return r;
}

// ---------------------------------------------------------------------------
__global__ __launch_bounds__(256) void k_prep_x(const float* __restrict__ x,
                                                f16_t* __restrict__ xT) {
  __shared__ f16_t sx[64][IDIM + 8];
  const int t = blockIdx.x;
  const int tid = threadIdx.x;
#pragma unroll 4
  for (int b = 0; b < 64; ++b)
    sx[b][tid] = (f16_t)x[((size_t)b * TLEN + t) * IDIM + tid];
  __syncthreads();
#pragma unroll
  for (int it = 0; it < 8; ++it) {
    const int c = it * 256 + tid;      // c = kk4*64 + b
    const int b = c & 63, kk4 = c >> 6;
    half8 v = *(const half8*)&sx[b][kk4 * 8];
    *(half8*)(xT + (((size_t)t * 32 + kk4) * 64 + b) * 8) = v;
  }
}

__global__ __launch_bounds__(256) void k_prep_w(const float* __restrict__ Wa,
                                                f16_t* __restrict__ WaT) {
  const int id = blockIdx.x * 256 + threadIdx.x;   // 0..32767
  const int n = id & 511, kk4 = id >> 9;
  half8 v = load_cvt8(&Wa[(size_t)n * HDIM + kk4 * 8]);
  *(half8*)(WaT + ((size_t)kk4 * HDIM + n) * 8) = v;
}

// ---------------------------------------------------------------------------
// Recurrence. Block id = bg*16+ug: batches bg*16..+15, units ug*32..+31.
// Wave w computes units u0=ug*32+w*4..+3 (M rows [unit][gate]; C row q*4+r
// -> unit q, gate r => gate/cell update lane-local, c in fp32 reg for all T)
// and consumes producers {2w, 2w+1} (poll + 2KB load -> LDS).
// ---------------------------------------------------------------------------
__global__ __launch_bounds__(512, 2) void k_lstm(
    const float* __restrict__ Whh, const float* __restrict__ Wih,
    const float* __restrict__ bih, const float* __restrict__ bhh,
    const f16_t* __restrict__ xT, f16_t* __restrict__ hs,
    unsigned int* __restrict__ bar) {
  const int tid = threadIdx.x;
  const int w = tid >> 6;
  const int L = tid & 63;
  const int q = L >> 4, col = L & 15;
  const int bg = blockIdx.x >> 4;            // 0..3  batch group (chain)
  const int ug = blockIdx.x & 15;            // 0..15 unit group
  const int u0 = ug * 32 + w * 4;
  const int b = bg * 16 + col;
  const int myu = u0 + q;
  unsigned int* chainflags = bar + (size_t)bg * 16;   // 64B line, 16 dwords

  __shared__ __align__(16) f16_t hin[16][520];  // h(t-1): 1040B stride
  __shared__ __align__(16) f16_t hout[16][40];  // block's h(t) chunk

  // consumer-role mapping: wave w loads producers p = 2w + (L>>5)
  const int p = 2 * w + (L >> 5);            // producer 0..15
  const int lb = (L & 31) >> 1;              // batch row 0..15
  const int hc = L & 1;                      // 16-unit half of the 64B line
  const int uoff = p * 32 + hc * 16;         // unit offset of this lane's 32B

  // Persistent A-fragments: A[m=lane&15][k=q*8+j]; m = unit_local*4 + gate.
  const int arow = (col & 3) * HDIM + u0 + (col >> 2);
  half8 wAh[16], wAx[8];
#pragma unroll
  for (int kk = 0; kk < 16; ++kk)
    wAh[kk] = load_cvt8(&Whh[(size_t)arow * HDIM + kk * 32 + q * 8]);
#pragma unroll
  for (int kk = 0; kk < 8; ++kk)
    wAx[kk] = load_cvt8(&Wih[(size_t)arow * IDIM + kk * 32 + q * 8]);

  float pb[4];
#pragma unroll
  for (int r = 0; r < 4; ++r) pb[r] = bih[r * HDIM + myu] + bhh[r * HDIM + myu];

  auto xgemm = [&](int t) {
    f32x4 a = {0.f, 0.f, 0.f, 0.f};
#pragma unroll
    for (int kk = 0; kk < 8; ++kk) {
      half8 bf = *(const half8*)(xT +
          (((size_t)(t - 1) * 32 + kk * 4 + q) * 64 + b) * 8);
      a = MFMA16(wAx[kk], bf, a);
    }
    return a;
  };

  float c = 0.f;
  f32x4 xacc = xgemm(1);
  for (int t = 1; t <= TLEN; ++t) {
    // ---- wave-local: poll OUR 2 producers' flags (one coalesced dwordx2) --
    if (t > 1) {
      const unsigned tgt = (unsigned)(t - 1);
      const unsigned int* fl = chainflags + 2 * w;   // 8B aligned
      int guard = 0;
      for (;;) {
        uint2v v;
        asm volatile("global_load_dwordx2 %0, %1, off sc0 sc1\n\t"
                     "s_waitcnt vmcnt(0)"
                     : "=&v"(v) : "v"(fl) : "memory");
        if (v[0] >= tgt && v[1] >= tgt) break;
        if (++guard > (1 << 25)) break;        // fail loud, not hung
      }
    }

    // ---- wave-local: load OUR producers' 2KB of h(t-1) -> LDS ----
    {
      const f16_t* src = hs + ((size_t)(t - 1) * BATCH + bg * 16 + lb) * HDIM
                         + uoff;               // 32B per lane
      f32x4 v0, v1;
      asm volatile("global_load_dwordx4 %0, %2, off sc0 sc1\n\t"
                   "global_load_dwordx4 %1, %2, off offset:16 sc0 sc1\n\t"
                   "s_waitcnt vmcnt(0)"
                   : "=&v"(v0), "=&v"(v1) : "v"(src) : "memory");
      *(f32x4*)&hin[lb][uoff] = v0;
      *(f32x4*)&hin[lb][uoff + 8] = v1;
    }
    __syncthreads();                           // hin complete (all waves)

    // ---- MFMA: B-frags broadcast-read from LDS, quad accumulators ----
    f32x4 a0 = xacc, a1 = {0.f, 0.f, 0.f, 0.f};
    f32x4 a2 = {0.f, 0.f, 0.f, 0.f}, a3 = {0.f, 0.f, 0.f, 0.f};
#pragma unroll
    for (int kk = 0; kk < 16; kk += 4) {
      half8 b0 = *(const half8*)&hin[col][kk * 32 + q * 8];
      half8 b1 = *(const half8*)&hin[col][(kk + 1) * 32 + q * 8];
      half8 b2 = *(const half8*)&hin[col][(kk + 2) * 32 + q * 8];
      half8 b3 = *(const half8*)&hin[col][(kk + 3) * 32 + q * 8];
      a0 = MFMA16(wAh[kk], b0, a0);
      a1 = MFMA16(wAh[kk + 1], b1, a1);
      a2 = MFMA16(wAh[kk + 2], b2, a2);
      a3 = MFMA16(wAh[kk + 3], b3, a3);
    }
    const f32x4 acc = (a0 + a1) + (a2 + a3);

    const float ig = sigf(acc[0] + pb[0]);
    const float fg = sigf(acc[1] + pb[1]);
    const float gg = tanh_fast(acc[2] + pb[2]);
    const float og = sigf(acc[3] + pb[3]);
    c = fg * c + ig * gg;
    hout[col][w * 4 + q] = (f16_t)(og * tanh_fast(c));

    __syncthreads();                           // hout ready, hin consumed

    // ---- wave 0: 16 coalesced 64B stores + drain + flag=t ----
    if (w == 0) {
      const int sb = L >> 2, q4 = L & 3;
      f32x4 v = *(const f32x4*)&hout[sb][q4 * 8];
      f16_t* dst = hs + ((size_t)t * BATCH + bg * 16 + sb) * HDIM
                   + ug * 32 + q4 * 8;
      asm volatile("global_store_dwordx4 %0, %1, off sc0 sc1"
                   :: "v"(dst), "v"(v) : "memory");
      asm volatile("s_waitcnt vmcnt(0)" ::: "memory");
      if (L == 0) {
        unsigned tv = (unsigned)t;
        asm volatile("global_store_dword %0, %1, off sc0 sc1"
                     :: "v"(chainflags + ug), "v"(tv) : "memory");
      }
    }

    // x-projection for the NEXT step: overlaps other blocks' store/flag
    if (t < TLEN) xacc = xgemm(t + 1);
  }
}

// ---------------------------------------------------------------------------
__global__ __launch_bounds__(256) void k_attn(
    const f16_t* __restrict__ hse, const f16_t* __restrict__ WaT,
    const float* __restrict__ battn, f16_t* __restrict__ E) {
  const int w = threadIdx.x >> 6;
  const int L = threadIdx.x & 63;
  const int q = L >> 4, col = L & 15;
  const int m0 = blockIdx.x * 64 + w * 16;   // r rows (r = t*64+b)
  const int n0 = blockIdx.y * 64;            // h cols

  f32x4 acc[4];
#pragma unroll
  for (int nt = 0; nt < 4; ++nt) acc[nt] = {0.f, 0.f, 0.f, 0.f};

#pragma unroll 4
  for (int kk = 0; kk < 16; ++kk) {          // K = 512
    half8 af = *(const half8*)(hse + (size_t)(m0 + col) * HDIM + kk * 32 + q * 8);
#pragma unroll
    for (int nt = 0; nt < 4; ++nt) {
      half8 bf = *(const half8*)(WaT +
          ((size_t)(kk * 4 + q) * HDIM + n0 + nt * 16 + col) * 8);
      acc[nt] = MFMA16(af, bf, acc[nt]);
    }
  }
#pragma unroll
  for (int nt = 0; nt < 4; ++nt) {
    const int h = n0 + nt * 16 + col;
    const float bias = battn[h];
#pragma unroll
    for (int r = 0; r < 4; ++r) {
      const int m = m0 + q * 4 + r;
      E[(size_t)m * HDIM + h] = (f16_t)__expf(tanh_fast(acc[nt][r] + bias));
    }
  }
}

__global__ __launch_bounds__(256) void k_pool(
    const f16_t* __restrict__ E, const f16_t* __restrict__ hse,
    float* __restrict__ pnum, float* __restrict__ pden) {
  const int b = blockIdx.x;
  const int hc = blockIdx.y;
  const int tc = blockIdx.z;
  const int h = hc * 256 + threadIdx.x;
  float num = 0.f, den = 0.f;
#pragma unroll 4
  for (int tt = 0; tt < 256; ++tt) {
    const int t = tc * 256 + tt;
    const size_t idx = ((size_t)t * BATCH + b) * HDIM + h;
    const float e = (float)E[idx];
    const float hv = (float)hse[idx];
    den += e;
    num += e * hv;
  }
  const size_t pi = ((size_t)tc * BATCH + b) * HDIM + h;
  pnum[pi] = num;
  pden[pi] = den;
}

__global__ __launch_bounds__(256) void k_final(
    const float* __restrict__ pnum, const float* __restrict__ pden,
    float* __restrict__ out) {
  const int i = blockIdx.x * 256 + threadIdx.x;   // b*512+h
  float n = 0.f, d = 0.f;
#pragma unroll
  for (int z = 0; z < 4; ++z) {
    n += pnum[(size_t)z * 32768 + i];
    d += pden[(size_t)z * 32768 + i];
  }
  out[i] = n / d;
}

// ---------------------------------------------------------------------------
extern "C" void kernel_launch(void* const* d_in, const int* in_sizes, int n_in,
                              void* d_out, int out_size, void* d_ws, size_t ws_size,
                              hipStream_t stream) {
  const float* x   = (const float*)d_in[0];
  const float* Wih = (const float*)d_in[1];
  const float* Whh = (const float*)d_in[2];
  const float* bih = (const float*)d_in[3];
  const float* bhh = (const float*)d_in[4];
  const float* Wat = (const float*)d_in[5];
  const float* bat = (const float*)d_in[6];
  float* out = (float*)d_out;

  char* ws = (char*)d_ws;
  const size_t REGA_BYTES = (size_t)64 * 1024 * 1024;                        // xT then E
  const size_t HS_BYTES = (size_t)(TLEN + 1) * BATCH * HDIM * sizeof(f16_t); // 67.2MB
  const size_t WAT_BYTES = (size_t)64 * HDIM * 8 * sizeof(f16_t);            // 512KB
  const size_t P_BYTES = (size_t)4 * BATCH * HDIM * sizeof(float);           // 512KB

  f16_t* xT = (f16_t*)ws;
  f16_t* E  = (f16_t*)ws;
  f16_t* hs = (f16_t*)(ws + REGA_BYTES);
  f16_t* WaT = (f16_t*)(ws + REGA_BYTES + HS_BYTES);
  float* pnum = (float*)(ws + REGA_BYTES + HS_BYTES + WAT_BYTES);
  float* pden = (float*)(ws + REGA_BYTES + HS_BYTES + WAT_BYTES + P_BYTES);
  unsigned int* bar = (unsigned int*)(ws + REGA_BYTES + HS_BYTES + WAT_BYTES + 2 * P_BYTES);

  hipMemsetAsync(hs, 0, (size_t)BATCH * HDIM * sizeof(f16_t), stream);
  hipMemsetAsync(bar, 0, 512, stream);   // 4 chains x 16 flag dwords

  k_prep_x<<<dim3(TLEN), 256, 0, stream>>>(x, xT);
  k_prep_w<<<dim3(128), 256, 0, stream>>>(Wat, WaT);
  k_lstm<<<dim3(64), 512, 0, stream>>>(Whh, Wih, bih, bhh, xT, hs, bar);

  const f16_t* hse = hs + (size_t)BATCH * HDIM;   // slab 1 == reference hs[0]
  k_attn<<<dim3(1024, 8), 256, 0, stream>>>(hse, WaT, bat, E);
  k_pool<<<dim3(64, 2, 4), 256, 0, stream>>>(E, hse, pnum, pden);
  k_final<<<dim3(128), 256, 0, stream>>>(pnum, pden, out);
}